// Round 2
// baseline (212.023 us; speedup 1.0000x reference)
//
#include <hip/hip_runtime.h>

#define NROWS 8192
#define DDIM 256
#define BT 128
#define BK 64
#define GT (NROWS / BT)            // 64 tile-rows
#define NBT (GT * (GT + 1) / 2)    // 2080 upper-triangle blocks
#define NCLS 512

using bf16x8 = __attribute__((ext_vector_type(8))) __bf16;
using f32x4  = __attribute__((ext_vector_type(4))) float;

__device__ __forceinline__ void glds16(const unsigned short* g, unsigned short* l) {
    // async global->LDS DMA, 16B/lane; LDS dest = wave-uniform base + lane*16
    __builtin_amdgcn_global_load_lds(
        (const __attribute__((address_space(1))) unsigned int*)g,
        (__attribute__((address_space(3))) unsigned int*)l,
        16, 0, 0);
}

__device__ __forceinline__ unsigned short f2bf(float f) {
    unsigned int b = __float_as_uint(f);
    unsigned int r = b + 0x7fffu + ((b >> 16) & 1u);
    return (unsigned short)(r >> 16);
}
__device__ __forceinline__ float bf2f(unsigned short u) {
    return __uint_as_float((unsigned)u << 16);
}

// Kernel 1: one wave per row. Normalize, CENTER (e - mean), emit bf16 e~,
// and per-row epilogue constants:
//   dist_ij = (b_i + b_j - (e~_i . e~_j)/128) / b_i
//   v_neg(i,j) = 0.2 - dist_ij = fmaf(aP_i, acc + bs_j, c_i)
//   with aP = (1/b)/128, bs = -128*b, c = aP*bs + 0.2
__global__ __launch_bounds__(256) void rowstats_kernel(
    const float* __restrict__ x, unsigned short* __restrict__ ebf,
    float* __restrict__ aP, float* __restrict__ bs,
    float* __restrict__ cA, float* __restrict__ rabs)
{
    int wave = threadIdx.x >> 6;
    int lane = threadIdx.x & 63;
    int row  = blockIdx.x * 4 + wave;

    const float4 v = reinterpret_cast<const float4*>(x + (size_t)row * DDIM)[lane];
    float ss = v.x * v.x + v.y * v.y + v.z * v.z + v.w * v.w;
    float sm = v.x + v.y + v.z + v.w;
    #pragma unroll
    for (int off = 32; off >= 1; off >>= 1) {
        ss += __shfl_xor(ss, off);
        sm += __shfl_xor(sm, off);
    }
    float invn = 1.0f / sqrtf(ss);
    float m = sm * invn * (1.0f / DDIM);

    ushort4 o;
    o.x = f2bf(v.x * invn - m);
    o.y = f2bf(v.y * invn - m);
    o.z = f2bf(v.z * invn - m);
    o.w = f2bf(v.w * invn - m);
    reinterpret_cast<ushort4*>(ebf + (size_t)row * DDIM)[lane] = o;

    if (lane == 0) {
        float s  = ss * invn * invn * (1.0f / DDIM);
        float b  = s - m * m;
        float a  = 1.0f / b;
        float ap = a * (1.0f / 128.0f);
        float bv = -128.0f * b;
        aP[row]   = ap;
        bs[row]   = bv;
        cA[row]   = fmaf(ap, bv, 0.2f);
        rabs[row] = fabsf(sm * invn);
    }
}

// Kernel 2: upper-triangle E~.E~^T bf16 MFMA GEMM + label-free neg-only epilogue.
// Every ordered pair gets neg treatment; same-label pairs are fixed up by corr_kernel.
__global__ __launch_bounds__(256) void snr_gemm_kernel(
    const unsigned short* __restrict__ ebf,
    const float* __restrict__ aP, const float* __restrict__ bs,
    const float* __restrict__ cA,
    float* __restrict__ partials)
{
    __shared__ __align__(16) unsigned short As[BT * BK];   // 16 KB, swizzled chunks
    __shared__ __align__(16) unsigned short Bs[BT * BK];   // 16 KB
    __shared__ float sAPi[BT], sBsi[BT], sCi[BT];
    __shared__ float sAPj[BT], sBsj[BT], sCj[BT];
    __shared__ float redbuf[4][2];

    int tid  = threadIdx.x;
    int lane = tid & 63;
    int wave = tid >> 6;
    int wr = (wave >> 1) * 64;
    int wc = (wave & 1) * 64;

    // decode triangular block id -> (bi, bj), bi <= bj
    int t = blockIdx.x;
    int bi = (int)((2.0f * GT + 1.0f
                    - sqrtf((2.0f * GT + 1.0f) * (2.0f * GT + 1.0f) - 8.0f * (float)t)) * 0.5f);
    while ((bi + 1) * GT - ((bi + 1) * bi) / 2 <= t) ++bi;
    while (bi * GT - (bi * (bi - 1)) / 2 > t) --bi;
    int bj = bi + (t - (bi * GT - (bi * (bi - 1)) / 2));
    int rowBase = bi * BT, colBase = bj * BT;
    bool diag = (bi == bj);

    // stage per-row / per-col epilogue constants (covered by first K-loop barrier)
    if (tid < BT) {
        int gi = rowBase + tid;
        sAPi[tid] = aP[gi]; sBsi[tid] = bs[gi]; sCi[tid] = cA[gi];
    } else {
        int tt = tid - BT;
        int gj = colBase + tt;
        sAPj[tt] = aP[gj]; sBsj[tt] = bs[gj]; sCj[tt] = cA[gj];
    }

    // staging addresses: chunk q = p*256+tid; logical (row=q>>3, slot=q&7),
    // slot holds k-chunk kc = slot ^ (row&7)  (XOR swizzle, conflict-free frag reads)
    const unsigned short* gA[4];
    const unsigned short* gB[4];
    unsigned short* lpA[4];
    unsigned short* lpB[4];
    #pragma unroll
    for (int p = 0; p < 4; ++p) {
        int q   = p * 256 + tid;
        int row = q >> 3;
        int kc  = (q & 7) ^ (row & 7);
        gA[p] = ebf + (size_t)(rowBase + row) * DDIM + kc * 8;
        gB[p] = ebf + (size_t)(colBase + row) * DDIM + kc * 8;
        lpA[p] = As + q * 8;
        lpB[p] = Bs + q * 8;
    }

    // fragment LDS offsets (elems), swizzle-aware
    int mrow = lane & 15;
    int kch  = lane >> 4;          // 16B k-chunk within half
    int offA[4][2], offB[4][2];
    #pragma unroll
    for (int t4 = 0; t4 < 4; ++t4) {
        int rA = wr + t4 * 16 + mrow;
        int rB = wc + t4 * 16 + mrow;
        #pragma unroll
        for (int h = 0; h < 2; ++h) {
            offA[t4][h] = (rA * 8 + ((h * 4 + kch) ^ (rA & 7))) * 8;
            offB[t4][h] = (rB * 8 + ((h * 4 + kch) ^ (rB & 7))) * 8;
        }
    }

    f32x4 acc[4][4];
    #pragma unroll
    for (int a = 0; a < 4; ++a)
        #pragma unroll
        for (int b = 0; b < 4; ++b)
            acc[a][b] = (f32x4){0.f, 0.f, 0.f, 0.f};

    const unsigned short* Bfrag = diag ? &As[0] : &Bs[0];  // diag block: B-tile == A-tile

    for (int it = 0; it < 4; ++it) {
        #pragma unroll
        for (int p = 0; p < 4; ++p) {
            glds16(gA[p], lpA[p]);
            gA[p] += BK;
        }
        if (!diag) {
            #pragma unroll
            for (int p = 0; p < 4; ++p) {
                glds16(gB[p], lpB[p]);
                gB[p] += BK;
            }
        }
        asm volatile("s_waitcnt vmcnt(0)" ::: "memory");
        __syncthreads();

        #pragma unroll
        for (int h = 0; h < 2; ++h) {
            bf16x8 aF[4], bF[4];
            #pragma unroll
            for (int t4 = 0; t4 < 4; ++t4) {
                aF[t4] = *reinterpret_cast<const bf16x8*>(As + offA[t4][h]);
                bF[t4] = *reinterpret_cast<const bf16x8*>(Bfrag + offB[t4][h]);
            }
            #pragma unroll
            for (int ti = 0; ti < 4; ++ti)
                #pragma unroll
                for (int tj = 0; tj < 4; ++tj)
                    acc[ti][tj] = __builtin_amdgcn_mfma_f32_16x16x32_bf16(aF[ti], bF[tj], acc[ti][tj], 0, 0, 0);
        }
        __syncthreads();
    }

    // Epilogue: neg treatment for EVERY ordered pair (no labels here).
    // v_neg(i,j) = fmaf(aP_i, acc + bs_j, c_i);  off-diag blocks do both sides.
    int subr = (lane >> 4) * 4;
    int cj   = lane & 15;

    float aPC[4], bsC[4], cC[4];
    #pragma unroll
    for (int tj = 0; tj < 4; ++tj) {
        int lj = wc + tj * 16 + cj;
        aPC[tj] = sAPj[lj]; bsC[tj] = sBsj[lj]; cC[tj] = sCj[lj];
    }

    float S = 0.f;
    unsigned C = 0u;

    if (!diag) {
        #pragma unroll
        for (int ti = 0; ti < 4; ++ti) {
            float aPR[4], bsR[4], cR[4];
            #pragma unroll
            for (int r = 0; r < 4; ++r) {
                int li = wr + ti * 16 + subr + r;
                aPR[r] = sAPi[li]; bsR[r] = sBsi[li]; cR[r] = sCi[li];
            }
            #pragma unroll
            for (int tj = 0; tj < 4; ++tj) {
                #pragma unroll
                for (int r = 0; r < 4; ++r) {
                    float raw = acc[ti][tj][r];
                    float v1 = fmaf(aPR[r], raw + bsC[tj], cR[r]);   // side (i,j)
                    float v2 = fmaf(aPC[tj], raw + bsR[r], cC[tj]);  // side (j,i)
                    S += fmaxf(v1, 0.f) + fmaxf(v2, 0.f);
                    C += (v1 > 0.f);
                    C += (v2 > 0.f);
                }
            }
        }
    } else {
        #pragma unroll
        for (int ti = 0; ti < 4; ++ti) {
            float aPR[4], cR[4];
            #pragma unroll
            for (int r = 0; r < 4; ++r) {
                int li = wr + ti * 16 + subr + r;
                aPR[r] = sAPi[li]; cR[r] = sCi[li];
            }
            #pragma unroll
            for (int tj = 0; tj < 4; ++tj) {
                #pragma unroll
                for (int r = 0; r < 4; ++r) {
                    float raw = acc[ti][tj][r];
                    float v1 = fmaf(aPR[r], raw + bsC[tj], cR[r]);
                    S += fmaxf(v1, 0.f);
                    C += (v1 > 0.f);
                }
            }
        }
    }

    #pragma unroll
    for (int off = 32; off >= 1; off >>= 1) {
        S += __shfl_down(S, off);
        C += __shfl_down(C, off);
    }
    if (lane == 0) { redbuf[wave][0] = S; redbuf[wave][1] = (float)C; }
    __syncthreads();
    if (tid < 2) {
        partials[blockIdx.x * 2 + tid] =
            redbuf[0][tid] + redbuf[1][tid] + redbuf[2][tid] + redbuf[3][tid];
    }
}

// Kernel 3: sparse same-label correction. One block per label (~16 rows each).
// Subtracts the neg contributions the main kernel added for same-label pairs
// (incl. the diagonal) and adds the true pos contributions.
__global__ __launch_bounds__(256) void corr_kernel(
    const unsigned short* __restrict__ ebf,
    const float* __restrict__ aP, const float* __restrict__ bs,
    const int* __restrict__ labels,
    float* __restrict__ corr)
{
    __shared__ int rowsL[512];
    __shared__ int cntS;
    __shared__ float cred[4][4];
    int tid  = threadIdx.x;
    int lane = tid & 63;
    int wave = tid >> 6;
    int L = blockIdx.x;

    if (tid == 0) cntS = 0;
    __syncthreads();
    for (int i = tid; i < NROWS; i += 256)
        if (labels[i] == L) { int p = atomicAdd(&cntS, 1); if (p < 512) rowsL[p] = i; }
    __syncthreads();
    int n = min(cntS, 512);
    int T = n * (n + 1) / 2;   // unordered pairs incl. diagonal

    float Ssub = 0.f, Spos = 0.f;
    unsigned Csub = 0u, Cpos = 0u;

    for (int p = wave; p < T; p += 4) {
        int r1 = (int)((sqrtf(8.0f * (float)p + 1.0f) - 1.0f) * 0.5f);
        while ((r1 + 1) * (r1 + 2) / 2 <= p) ++r1;
        while (r1 * (r1 + 1) / 2 > p) --r1;
        int c = p - r1 * (r1 + 1) / 2;
        int u = rowsL[r1], v = rowsL[c];

        ushort4 eu = reinterpret_cast<const ushort4*>(ebf + (size_t)u * DDIM)[lane];
        ushort4 ev = reinterpret_cast<const ushort4*>(ebf + (size_t)v * DDIM)[lane];
        float dot = bf2f(eu.x) * bf2f(ev.x) + bf2f(eu.y) * bf2f(ev.y)
                  + bf2f(eu.z) * bf2f(ev.z) + bf2f(eu.w) * bf2f(ev.w);
        #pragma unroll
        for (int off = 32; off >= 1; off >>= 1) dot += __shfl_xor(dot, off);

        if (lane == 0) {
            float raw = dot + bs[u] + bs[v];
            float vn1 = fmaf(aP[u], raw, 0.2f);
            if (u == v) {
                // diagonal: main counted it as a neg; no pos term (eye excluded)
                Ssub += fmaxf(vn1, 0.f); Csub += (vn1 > 0.f);
            } else {
                float vn2 = fmaf(aP[v], raw, 0.2f);
                Ssub += fmaxf(vn1, 0.f) + fmaxf(vn2, 0.f);
                Csub += (vn1 > 0.f); Csub += (vn2 > 0.f);
                float vp1 = fmaf(-aP[u], raw, -0.01f);   // d_uv - 0.01
                float vp2 = fmaf(-aP[v], raw, -0.01f);   // d_vu - 0.01
                Spos += fmaxf(vp1, 0.f) + fmaxf(vp2, 0.f);
                Cpos += (vp1 > 0.f); Cpos += (vp2 > 0.f);
            }
        }
    }

    if (lane == 0) {
        cred[wave][0] = Ssub; cred[wave][1] = (float)Csub;
        cred[wave][2] = Spos; cred[wave][3] = (float)Cpos;
    }
    __syncthreads();
    if (tid < 4) {
        corr[L * 4 + tid] = cred[0][tid] + cred[1][tid] + cred[2][tid] + cred[3][tid];
    }
}

// Kernel 4: reduce per-block partials + corrections + reg term, emit scalar loss.
// Guards: if a count cancels to exactly 0, the true masked sum is exactly 0 too
// (reference yields 0/1e-12 = 0) — emit 0 instead of residual/1e-12.
__global__ __launch_bounds__(256) void finalize_kernel(
    const float* __restrict__ partials, const float* __restrict__ corr,
    const float* __restrict__ rabs, float* __restrict__ out)
{
    int tid = threadIdx.x;
    float sAll = 0, cAll = 0, sSub = 0, cSub = 0, sPos = 0, cPos = 0, rr = 0;
    for (int i = tid; i < NBT; i += 256) {
        float2 p = reinterpret_cast<const float2*>(partials)[i];
        sAll += p.x; cAll += p.y;
    }
    for (int i = tid; i < NCLS; i += 256) {
        float4 q = reinterpret_cast<const float4*>(corr)[i];
        sSub += q.x; cSub += q.y; sPos += q.z; cPos += q.w;
    }
    for (int i = tid; i < NROWS; i += 256) rr += rabs[i];

    #pragma unroll
    for (int off = 32; off >= 1; off >>= 1) {
        sAll += __shfl_down(sAll, off);
        cAll += __shfl_down(cAll, off);
        sSub += __shfl_down(sSub, off);
        cSub += __shfl_down(cSub, off);
        sPos += __shfl_down(sPos, off);
        cPos += __shfl_down(cPos, off);
        rr   += __shfl_down(rr, off);
    }
    __shared__ float red[4][7];
    int wave = tid >> 6, lane = tid & 63;
    if (lane == 0) {
        red[wave][0] = sAll; red[wave][1] = cAll; red[wave][2] = sSub;
        red[wave][3] = cSub; red[wave][4] = sPos; red[wave][5] = cPos;
        red[wave][6] = rr;
    }
    __syncthreads();
    if (tid == 0) {
        float a[7];
        #pragma unroll
        for (int k = 0; k < 7; ++k)
            a[k] = red[0][k] + red[1][k] + red[2][k] + red[3][k];
        float Sn = a[0] - a[2];
        float Cn = a[1] - a[3];
        float pos = (a[5] > 0.5f) ? a[4] / (a[5] + 1e-12f) : 0.0f;
        float neg = (Cn  > 0.5f) ? Sn   / (Cn  + 1e-12f) : 0.0f;
        out[0] = pos + neg + a[6] * (0.1f / (float)NROWS);
    }
}

extern "C" void kernel_launch(void* const* d_in, const int* in_sizes, int n_in,
                              void* d_out, int out_size, void* d_ws, size_t ws_size,
                              hipStream_t stream) {
    const float* embeds = (const float*)d_in[0];
    const int*   labels = (const int*)d_in[1];
    float* out = (float*)d_out;

    char* ws = (char*)d_ws;
    unsigned short* ebf = (unsigned short*)ws;                       // 4 MB
    float* aP   = (float*)(ws + (size_t)NROWS * DDIM * 2);
    float* bs   = aP + NROWS;
    float* cA   = bs + NROWS;
    float* rabs = cA + NROWS;
    float* partials = rabs + NROWS;                                  // NBT*2 floats
    float* corr = partials + (size_t)NBT * 2;                        // NCLS*4 floats

    rowstats_kernel<<<NROWS / 4, 256, 0, stream>>>(embeds, ebf, aP, bs, cA, rabs);

    corr_kernel<<<NCLS, 256, 0, stream>>>(ebf, aP, bs, labels, corr);

    snr_gemm_kernel<<<NBT, 256, 0, stream>>>(ebf, aP, bs, cA, partials);

    finalize_kernel<<<1, 256, 0, stream>>>(partials, corr, rabs, out);
}

// Round 3
// 157.834 us; speedup vs baseline: 1.3433x; 1.3433x over previous
//
#include <hip/hip_runtime.h>

#define NROWS 8192
#define DDIM 256
#define BT 128
#define BK 64
#define GT (NROWS / BT)            // 64 tile-rows
#define NBT (GT * (GT + 1) / 2)    // 2080 upper-triangle blocks
#define NCLS 512
#define LCAP 64                    // max rows per class cached (mean 16, sigma 4 -> 64 is +12 sigma)

using bf16x8 = __attribute__((ext_vector_type(8))) __bf16;
using u16x8  = __attribute__((ext_vector_type(8))) unsigned short;
using f32x4  = __attribute__((ext_vector_type(4))) float;

__device__ __forceinline__ void glds16(const unsigned short* g, unsigned short* l) {
    // async global->LDS DMA, 16B/lane; LDS dest = wave-uniform base + lane*16
    __builtin_amdgcn_global_load_lds(
        (const __attribute__((address_space(1))) unsigned int*)g,
        (__attribute__((address_space(3))) unsigned int*)l,
        16, 0, 0);
}

__device__ __forceinline__ unsigned short f2bf(float f) {
    unsigned int b = __float_as_uint(f);
    unsigned int r = b + 0x7fffu + ((b >> 16) & 1u);
    return (unsigned short)(r >> 16);
}
__device__ __forceinline__ float bf2f(unsigned short u) {
    return __uint_as_float((unsigned)u << 16);
}

// Kernel 1: one wave per row. Normalize, CENTER (e - mean), emit bf16 e~,
// and per-row epilogue constants:
//   dist_ij = (b_i + b_j - (e~_i . e~_j)/128) / b_i
//   v_neg(i,j) = 0.2 - dist_ij = fmaf(aP_i, acc + bs_j, c_i)
//   with aP = (1/b)/128, bs = -128*b, c = aP*bs + 0.2
__global__ __launch_bounds__(256) void rowstats_kernel(
    const float* __restrict__ x, unsigned short* __restrict__ ebf,
    float* __restrict__ aP, float* __restrict__ bs,
    float* __restrict__ cA, float* __restrict__ rabs)
{
    int wave = threadIdx.x >> 6;
    int lane = threadIdx.x & 63;
    int row  = blockIdx.x * 4 + wave;

    const float4 v = reinterpret_cast<const float4*>(x + (size_t)row * DDIM)[lane];
    float ss = v.x * v.x + v.y * v.y + v.z * v.z + v.w * v.w;
    float sm = v.x + v.y + v.z + v.w;
    #pragma unroll
    for (int off = 32; off >= 1; off >>= 1) {
        ss += __shfl_xor(ss, off);
        sm += __shfl_xor(sm, off);
    }
    float invn = 1.0f / sqrtf(ss);
    float m = sm * invn * (1.0f / DDIM);

    ushort4 o;
    o.x = f2bf(v.x * invn - m);
    o.y = f2bf(v.y * invn - m);
    o.z = f2bf(v.z * invn - m);
    o.w = f2bf(v.w * invn - m);
    reinterpret_cast<ushort4*>(ebf + (size_t)row * DDIM)[lane] = o;

    if (lane == 0) {
        float s  = ss * invn * invn * (1.0f / DDIM);
        float b  = s - m * m;
        float a  = 1.0f / b;
        float ap = a * (1.0f / 128.0f);
        float bv = -128.0f * b;
        aP[row]   = ap;
        bs[row]   = bv;
        cA[row]   = fmaf(ap, bv, 0.2f);
        rabs[row] = fabsf(sm * invn);
    }
}

// Kernel 2 (fused): blocks [0, NCLS) run the sparse same-label correction
// (LDS row cache + 16-lane-group pair parallelism); blocks [NCLS, NCLS+NBT)
// run the upper-triangle E~.E~^T bf16 MFMA GEMM with label-free neg-only
// epilogue. Latency-bound corr blocks hide under compute-bound GEMM blocks.
__global__ __launch_bounds__(256) void snr_main_kernel(
    const unsigned short* __restrict__ ebf,
    const float* __restrict__ aP, const float* __restrict__ bs,
    const float* __restrict__ cA, const int* __restrict__ labels,
    float* __restrict__ partials, float* __restrict__ corr)
{
    __shared__ __align__(16) unsigned short smem[BT * BK * 2];  // 32 KB: As|Bs or corr row cache
    __shared__ float sAPi[BT], sBsi[BT], sCi[BT];
    __shared__ float sAPj[BT], sBsj[BT], sCj[BT];
    __shared__ float redbuf[4][4];
    __shared__ int rowsL[LCAP];
    __shared__ int cntS;

    int tid  = threadIdx.x;
    int lane = tid & 63;
    int wave = tid >> 6;

    if (blockIdx.x < NCLS) {
        // ---------------- corr path: one block per label ----------------
        int L = blockIdx.x;
        if (tid == 0) cntS = 0;
        __syncthreads();
        for (int i = tid; i < NROWS; i += 256)
            if (labels[i] == L) { int p = atomicAdd(&cntS, 1); if (p < LCAP) rowsL[p] = i; }
        __syncthreads();
        int n = min(cntS, LCAP);

        // stage class rows into LDS cache (coalesced; 1 ushort4 per lane per row)
        unsigned short* rc = smem;
        for (int r = wave; r < n; r += 4) {
            ushort4 t4 = reinterpret_cast<const ushort4*>(ebf + (size_t)rowsL[r] * DDIM)[lane];
            reinterpret_cast<ushort4*>(rc + r * DDIM)[lane] = t4;
        }
        if (tid < n) { sAPi[tid] = aP[rowsL[tid]]; sBsi[tid] = bs[rowsL[tid]]; }
        __syncthreads();

        // 16 groups of 16 lanes; each group owns one unordered pair per round
        int grp = tid >> 4;
        int l16 = tid & 15;
        int T = n * (n + 1) / 2;   // unordered pairs incl. diagonal
        float Ssub = 0.f, Spos = 0.f, Csub = 0.f, Cpos = 0.f;

        for (int p = grp; p < T; p += 16) {
            int r1 = (int)((sqrtf(8.0f * (float)p + 1.0f) - 1.0f) * 0.5f);
            while ((r1 + 1) * (r1 + 2) / 2 <= p) ++r1;
            while (r1 * (r1 + 1) / 2 > p) --r1;
            int c = p - r1 * (r1 + 1) / 2;

            const unsigned short* ru = rc + r1 * DDIM + l16 * 16;
            const unsigned short* rv = rc + c  * DDIM + l16 * 16;
            float d = 0.f;
            #pragma unroll
            for (int h = 0; h < 2; ++h) {
                u16x8 a8 = *reinterpret_cast<const u16x8*>(ru + h * 8);
                u16x8 b8 = *reinterpret_cast<const u16x8*>(rv + h * 8);
                #pragma unroll
                for (int e = 0; e < 8; ++e)
                    d = fmaf(bf2f(a8[e]), bf2f(b8[e]), d);
            }
            d += __shfl_xor(d, 1);
            d += __shfl_xor(d, 2);
            d += __shfl_xor(d, 4);
            d += __shfl_xor(d, 8);

            if (l16 == 0) {
                float raw = d + sBsi[r1] + sBsi[c];
                float vn1 = fmaf(sAPi[r1], raw, 0.2f);
                if (r1 == c) {
                    // diagonal: main counted it as a neg; no pos term (eye excluded)
                    Ssub += fmaxf(vn1, 0.f); Csub += (vn1 > 0.f);
                } else {
                    float vn2 = fmaf(sAPi[c], raw, 0.2f);
                    Ssub += fmaxf(vn1, 0.f) + fmaxf(vn2, 0.f);
                    Csub += (vn1 > 0.f); Csub += (vn2 > 0.f);
                    float vp1 = fmaf(-sAPi[r1], raw, -0.01f);  // d_uv - 0.01
                    float vp2 = fmaf(-sAPi[c],  raw, -0.01f);  // d_vu - 0.01
                    Spos += fmaxf(vp1, 0.f) + fmaxf(vp2, 0.f);
                    Cpos += (vp1 > 0.f); Cpos += (vp2 > 0.f);
                }
            }
        }

        #pragma unroll
        for (int off = 32; off >= 1; off >>= 1) {
            Ssub += __shfl_down(Ssub, off);
            Csub += __shfl_down(Csub, off);
            Spos += __shfl_down(Spos, off);
            Cpos += __shfl_down(Cpos, off);
        }
        if (lane == 0) {
            redbuf[wave][0] = Ssub; redbuf[wave][1] = Csub;
            redbuf[wave][2] = Spos; redbuf[wave][3] = Cpos;
        }
        __syncthreads();
        if (tid < 4)
            corr[L * 4 + tid] = redbuf[0][tid] + redbuf[1][tid] + redbuf[2][tid] + redbuf[3][tid];
        return;
    }

    // ---------------- GEMM path ----------------
    unsigned short* As = smem;
    unsigned short* Bs = smem + BT * BK;
    int wr = (wave >> 1) * 64;
    int wc = (wave & 1) * 64;

    // decode triangular block id -> (bi, bj), bi <= bj
    int t = blockIdx.x - NCLS;
    int bi = (int)((2.0f * GT + 1.0f
                    - sqrtf((2.0f * GT + 1.0f) * (2.0f * GT + 1.0f) - 8.0f * (float)t)) * 0.5f);
    while ((bi + 1) * GT - ((bi + 1) * bi) / 2 <= t) ++bi;
    while (bi * GT - (bi * (bi - 1)) / 2 > t) --bi;
    int bj = bi + (t - (bi * GT - (bi * (bi - 1)) / 2));
    int rowBase = bi * BT, colBase = bj * BT;
    bool diag = (bi == bj);

    // stage per-row / per-col epilogue constants (covered by first K-loop barrier)
    if (tid < BT) {
        int gi = rowBase + tid;
        sAPi[tid] = aP[gi]; sBsi[tid] = bs[gi]; sCi[tid] = cA[gi];
    } else {
        int tt = tid - BT;
        int gj = colBase + tt;
        sAPj[tt] = aP[gj]; sBsj[tt] = bs[gj]; sCj[tt] = cA[gj];
    }

    // staging addresses: chunk q = p*256+tid; logical (row=q>>3, slot=q&7),
    // slot holds k-chunk kc = slot ^ (row&7)  (XOR swizzle, conflict-free frag reads)
    const unsigned short* gA[4];
    const unsigned short* gB[4];
    unsigned short* lpA[4];
    unsigned short* lpB[4];
    #pragma unroll
    for (int p = 0; p < 4; ++p) {
        int q   = p * 256 + tid;
        int row = q >> 3;
        int kc  = (q & 7) ^ (row & 7);
        gA[p] = ebf + (size_t)(rowBase + row) * DDIM + kc * 8;
        gB[p] = ebf + (size_t)(colBase + row) * DDIM + kc * 8;
        lpA[p] = As + q * 8;
        lpB[p] = Bs + q * 8;
    }

    // fragment LDS offsets (elems), swizzle-aware
    int mrow = lane & 15;
    int kch  = lane >> 4;          // 16B k-chunk within half
    int offA[4][2], offB[4][2];
    #pragma unroll
    for (int t4 = 0; t4 < 4; ++t4) {
        int rA = wr + t4 * 16 + mrow;
        int rB = wc + t4 * 16 + mrow;
        #pragma unroll
        for (int h = 0; h < 2; ++h) {
            offA[t4][h] = (rA * 8 + ((h * 4 + kch) ^ (rA & 7))) * 8;
            offB[t4][h] = (rB * 8 + ((h * 4 + kch) ^ (rB & 7))) * 8;
        }
    }

    f32x4 acc[4][4];
    #pragma unroll
    for (int a = 0; a < 4; ++a)
        #pragma unroll
        for (int b = 0; b < 4; ++b)
            acc[a][b] = (f32x4){0.f, 0.f, 0.f, 0.f};

    const unsigned short* Bfrag = diag ? &As[0] : &Bs[0];  // diag block: B-tile == A-tile

    for (int it = 0; it < 4; ++it) {
        #pragma unroll
        for (int p = 0; p < 4; ++p) {
            glds16(gA[p], lpA[p]);
            gA[p] += BK;
        }
        if (!diag) {
            #pragma unroll
            for (int p = 0; p < 4; ++p) {
                glds16(gB[p], lpB[p]);
                gB[p] += BK;
            }
        }
        asm volatile("s_waitcnt vmcnt(0)" ::: "memory");
        __syncthreads();

        #pragma unroll
        for (int h = 0; h < 2; ++h) {
            bf16x8 aF[4], bF[4];
            #pragma unroll
            for (int t4 = 0; t4 < 4; ++t4) {
                aF[t4] = *reinterpret_cast<const bf16x8*>(As + offA[t4][h]);
                bF[t4] = *reinterpret_cast<const bf16x8*>(Bfrag + offB[t4][h]);
            }
            #pragma unroll
            for (int ti = 0; ti < 4; ++ti)
                #pragma unroll
                for (int tj = 0; tj < 4; ++tj)
                    acc[ti][tj] = __builtin_amdgcn_mfma_f32_16x16x32_bf16(aF[ti], bF[tj], acc[ti][tj], 0, 0, 0);
        }
        __syncthreads();
    }

    // Epilogue: neg treatment for EVERY ordered pair (no labels here).
    // v_neg(i,j) = fmaf(aP_i, acc + bs_j, c_i);  off-diag blocks do both sides.
    int subr = (lane >> 4) * 4;
    int cj   = lane & 15;

    float aPC[4], bsC[4], cC[4];
    #pragma unroll
    for (int tj = 0; tj < 4; ++tj) {
        int lj = wc + tj * 16 + cj;
        aPC[tj] = sAPj[lj]; bsC[tj] = sBsj[lj]; cC[tj] = sCj[lj];
    }

    float S = 0.f;
    unsigned C = 0u;

    if (!diag) {
        #pragma unroll
        for (int ti = 0; ti < 4; ++ti) {
            float aPR[4], bsR[4], cR[4];
            #pragma unroll
            for (int r = 0; r < 4; ++r) {
                int li = wr + ti * 16 + subr + r;
                aPR[r] = sAPi[li]; bsR[r] = sBsi[li]; cR[r] = sCi[li];
            }
            #pragma unroll
            for (int tj = 0; tj < 4; ++tj) {
                #pragma unroll
                for (int r = 0; r < 4; ++r) {
                    float raw = acc[ti][tj][r];
                    float v1 = fmaf(aPR[r], raw + bsC[tj], cR[r]);   // side (i,j)
                    float v2 = fmaf(aPC[tj], raw + bsR[r], cC[tj]);  // side (j,i)
                    S += fmaxf(v1, 0.f) + fmaxf(v2, 0.f);
                    C += (v1 > 0.f);
                    C += (v2 > 0.f);
                }
            }
        }
    } else {
        #pragma unroll
        for (int ti = 0; ti < 4; ++ti) {
            float aPR[4], cR[4];
            #pragma unroll
            for (int r = 0; r < 4; ++r) {
                int li = wr + ti * 16 + subr + r;
                aPR[r] = sAPi[li]; cR[r] = sCi[li];
            }
            #pragma unroll
            for (int tj = 0; tj < 4; ++tj) {
                #pragma unroll
                for (int r = 0; r < 4; ++r) {
                    float raw = acc[ti][tj][r];
                    float v1 = fmaf(aPR[r], raw + bsC[tj], cR[r]);
                    S += fmaxf(v1, 0.f);
                    C += (v1 > 0.f);
                }
            }
        }
    }

    #pragma unroll
    for (int off = 32; off >= 1; off >>= 1) {
        S += __shfl_down(S, off);
        C += __shfl_down(C, off);
    }
    if (lane == 0) { redbuf[wave][0] = S; redbuf[wave][1] = (float)C; }
    __syncthreads();
    if (tid < 2) {
        partials[t * 2 + tid] =
            redbuf[0][tid] + redbuf[1][tid] + redbuf[2][tid] + redbuf[3][tid];
    }
}

// Kernel 3: reduce per-block partials + corrections + reg term, emit scalar loss.
// Guards: if a count cancels to exactly 0, the true masked sum is exactly 0 too
// (reference yields 0/1e-12 = 0) — emit 0 instead of residual/1e-12.
__global__ __launch_bounds__(256) void finalize_kernel(
    const float* __restrict__ partials, const float* __restrict__ corr,
    const float* __restrict__ rabs, float* __restrict__ out)
{
    int tid = threadIdx.x;
    float sAll = 0, cAll = 0, sSub = 0, cSub = 0, sPos = 0, cPos = 0, rr = 0;
    for (int i = tid; i < NBT; i += 256) {
        float2 p = reinterpret_cast<const float2*>(partials)[i];
        sAll += p.x; cAll += p.y;
    }
    for (int i = tid; i < NCLS; i += 256) {
        float4 q = reinterpret_cast<const float4*>(corr)[i];
        sSub += q.x; cSub += q.y; sPos += q.z; cPos += q.w;
    }
    for (int i = tid; i < NROWS; i += 256) rr += rabs[i];

    #pragma unroll
    for (int off = 32; off >= 1; off >>= 1) {
        sAll += __shfl_down(sAll, off);
        cAll += __shfl_down(cAll, off);
        sSub += __shfl_down(sSub, off);
        cSub += __shfl_down(cSub, off);
        sPos += __shfl_down(sPos, off);
        cPos += __shfl_down(cPos, off);
        rr   += __shfl_down(rr, off);
    }
    __shared__ float red[4][7];
    int wave = tid >> 6, lane = tid & 63;
    if (lane == 0) {
        red[wave][0] = sAll; red[wave][1] = cAll; red[wave][2] = sSub;
        red[wave][3] = cSub; red[wave][4] = sPos; red[wave][5] = cPos;
        red[wave][6] = rr;
    }
    __syncthreads();
    if (tid == 0) {
        float a[7];
        #pragma unroll
        for (int k = 0; k < 7; ++k)
            a[k] = red[0][k] + red[1][k] + red[2][k] + red[3][k];
        float Sn = a[0] - a[2];
        float Cn = a[1] - a[3];
        float pos = (a[5] > 0.5f) ? a[4] / (a[5] + 1e-12f) : 0.0f;
        float neg = (Cn  > 0.5f) ? Sn   / (Cn  + 1e-12f) : 0.0f;
        out[0] = pos + neg + a[6] * (0.1f / (float)NROWS);
    }
}

extern "C" void kernel_launch(void* const* d_in, const int* in_sizes, int n_in,
                              void* d_out, int out_size, void* d_ws, size_t ws_size,
                              hipStream_t stream) {
    const float* embeds = (const float*)d_in[0];
    const int*   labels = (const int*)d_in[1];
    float* out = (float*)d_out;

    char* ws = (char*)d_ws;
    unsigned short* ebf = (unsigned short*)ws;                       // 4 MB
    float* aP   = (float*)(ws + (size_t)NROWS * DDIM * 2);
    float* bs   = aP + NROWS;
    float* cA   = bs + NROWS;
    float* rabs = cA + NROWS;
    float* partials = rabs + NROWS;                                  // NBT*2 floats
    float* corr = partials + (size_t)NBT * 2;                        // NCLS*4 floats

    rowstats_kernel<<<NROWS / 4, 256, 0, stream>>>(embeds, ebf, aP, bs, cA, rabs);

    snr_main_kernel<<<NCLS + NBT, 256, 0, stream>>>(ebf, aP, bs, cA, labels, partials, corr);

    finalize_kernel<<<1, 256, 0, stream>>>(partials, corr, rabs, out);
}